// Round 11
// baseline (189.540 us; speedup 1.0000x reference)
//
#include <hip/hip_runtime.h>
#include <hip/hip_fp16.h>
#include <math.h>

#define N_NODES 50000
#define N_EDGES 1600000
#define BSH 8                                   // 256 nodes per bucket
#define NBUCK ((N_NODES + 255) >> BSH)          // 196
#define EPB 4096                                // edges per scatter/hist block
#define NBLK ((N_EDGES + EPB - 1) / EPB)        // 391

// ================= CSR build (atomic-free at global scope) =================

__global__ __launch_bounds__(256) void bucket_hist(const int* __restrict__ dst,
                                                   int* __restrict__ bhist_t, int e) {
    __shared__ int h[NBUCK];
    for (int i = threadIdx.x; i < NBUCK; i += 256) h[i] = 0;
    __syncthreads();
    int base = blockIdx.x * EPB;
#pragma unroll
    for (int j = 0; j < EPB / 256; ++j) {
        int i = base + j * 256 + threadIdx.x;
        if (i < e) atomicAdd(&h[dst[i] >> BSH], 1);
    }
    __syncthreads();
    for (int i = threadIdx.x; i < NBUCK; i += 256)
        bhist_t[i * NBLK + blockIdx.x] = h[i];
}

__global__ __launch_bounds__(256) void bucket_totals(const int* __restrict__ bhist_t,
                                                     int* __restrict__ btot) {
    int b = blockIdx.x;
    const int* col = bhist_t + (size_t)b * NBLK;
    int s = 0;
    for (int i = threadIdx.x; i < NBLK; i += 256) s += col[i];
#pragma unroll
    for (int off = 1; off < 64; off <<= 1) s += __shfl_xor(s, off);
    __shared__ int red[4];
    if ((threadIdx.x & 63) == 0) red[threadIdx.x >> 6] = s;
    __syncthreads();
    if (threadIdx.x == 0)
        btot[b] = red[0] + red[1] + red[2] + red[3];
}

// one wave per bucket: internal prefix over btot, then column scan + rewrite
__global__ __launch_bounds__(64) void rewrite_offsets(int* __restrict__ bhist_t,
                                                      const int* __restrict__ btot,
                                                      int* __restrict__ rowptr) {
    int b = blockIdx.x;
    int lane = threadIdx.x;
    int pre = 0;                                  // bbase[b] computed in-wave
    for (int i = lane; i < NBUCK; i += 64) if (i < b) pre += btot[i];
#pragma unroll
    for (int off = 1; off < 64; off <<= 1) pre += __shfl_xor(pre, off);
    if (b == 0 && lane == 0) rowptr[N_NODES] = N_EDGES;

    int* col = bhist_t + (size_t)b * NBLK;
    __shared__ int buf[NBLK];
    for (int i = lane; i < NBLK; i += 64) buf[i] = col[i];
    __syncthreads();
    constexpr int CH = (NBLK + 63) / 64;
    int lo = lane * CH;
    int hi = lo + CH; if (hi > NBLK) hi = NBLK;
    int s = 0;
    for (int i = lo; i < hi; ++i) s += buf[i];
    int inc = s;
#pragma unroll
    for (int off = 1; off < 64; off <<= 1) {
        int t = __shfl_up(inc, off);
        if (lane >= off) inc += t;
    }
    int run = pre + inc - s;
    for (int i = lo; i < hi; ++i) { int c = buf[i]; col[i] = run; run += c; }
}

__global__ __launch_bounds__(256) void bucket_scatter(const int* __restrict__ src,
                                                      const int* __restrict__ dst,
                                                      const int* __restrict__ bhist_t,
                                                      unsigned* __restrict__ packed, int e) {
    __shared__ int lcur[NBUCK];
    int r = blockIdx.x;
    for (int i = threadIdx.x; i < NBUCK; i += 256)
        lcur[i] = bhist_t[i * NBLK + r];
    __syncthreads();
    int base = r * EPB;
#pragma unroll
    for (int j = 0; j < EPB / 256; ++j) {
        int i = base + j * 256 + threadIdx.x;
        if (i < e) {
            int d = dst[i];
            int pos = atomicAdd(&lcur[d >> BSH], 1);
            packed[pos] = (unsigned)src[i] | ((unsigned)(d & ((1 << BSH) - 1)) << 16);
        }
    }
}

__global__ __launch_bounds__(512) void csr_finalize(const unsigned* __restrict__ packed,
                                                    const int* __restrict__ btot,
                                                    int* __restrict__ rowptr,
                                                    int* __restrict__ csr_src) {
    int b = blockIdx.x;
    __shared__ int sb[2];
    if (threadIdx.x < 64) {                       // wave 0: prefix over btot
        int pre = 0, tot = 0;
        for (int i = threadIdx.x; i < NBUCK; i += 64) {
            int v = btot[i];
            if (i < b) pre += v;
            if (i == b) tot = v;
        }
#pragma unroll
        for (int off = 1; off < 64; off <<= 1) {
            pre += __shfl_xor(pre, off);
            tot += __shfl_xor(tot, off);
        }
        if (threadIdx.x == 0) { sb[0] = pre; sb[1] = pre + tot; }
    }
    __syncthreads();
    int s0 = sb[0], s1 = sb[1];
    int cnt = s1 - s0;
    __shared__ int ncnt[256];
    __shared__ int ncur[256];
    __shared__ int wsum[4];
    if (threadIdx.x < 256) ncnt[threadIdx.x] = 0;
    __syncthreads();
    for (int i = threadIdx.x; i < cnt; i += 512)
        atomicAdd(&ncnt[packed[s0 + i] >> 16], 1);
    __syncthreads();
    int lane = threadIdx.x & 63, w = threadIdx.x >> 6;
    int v = 0, inc = 0;
    if (threadIdx.x < 256) {
        v = ncnt[threadIdx.x]; inc = v;
#pragma unroll
        for (int off = 1; off < 64; off <<= 1) {
            int t = __shfl_up(inc, off);
            if (lane >= off) inc += t;
        }
        if (lane == 63) wsum[w] = inc;
    }
    __syncthreads();
    if (threadIdx.x < 256) {
        int woff = 0;
#pragma unroll
        for (int k = 0; k < 3; ++k) if (k < w) woff += wsum[k];
        int excl = woff + inc - v;
        int node = (b << BSH) + threadIdx.x;
        if (node < N_NODES) rowptr[node] = s0 + excl;
        ncur[threadIdx.x] = s0 + excl;
    }
    __syncthreads();
    for (int i = threadIdx.x; i < cnt; i += 512) {
        unsigned p = packed[s0 + i];
        int pos = atomicAdd(&ncur[p >> 16], 1);
        csr_src[pos] = (int)(p & 0xFFFFu);
    }
}

// ================= register-tiled GEMM + fused alpha =================
// IN_HALF: input activations fp16; OUT_HALF: h table stored fp16.
// All accumulation + as_/ad_ stay fp32.

template<int K, int C, bool IN_HALF, bool OUT_HALF>
__global__ __launch_bounds__(256) void gemm_alpha(
        const void* __restrict__ inv, const float* __restrict__ W,
        const float* __restrict__ a_src, const float* __restrict__ a_dst,
        void* __restrict__ hv, float* __restrict__ as_, float* __restrict__ ad_, int n)
{
    constexpr int CPT = C / 16;
    constexpr int KP = K + 4;
    __shared__ float sx[64][KP];
    __shared__ float sW[K * C];
    int row0 = blockIdx.x * 64;
    int nvalid = n - row0;

    if constexpr (IN_HALF) {
        const __half* inh = (const __half*)inv;
        for (int idx = threadIdx.x; idx < 64 * K / 8; idx += 256) {
            int r = idx / (K / 8), kc = idx % (K / 8);
            uint4 v = {0u, 0u, 0u, 0u};
            if (r < nvalid) v = *(const uint4*)&inh[(size_t)(row0 + r) * K + kc * 8];
            float2 f0 = __half22float2(*(__half2*)&v.x);
            float2 f1 = __half22float2(*(__half2*)&v.y);
            float2 f2 = __half22float2(*(__half2*)&v.z);
            float2 f3 = __half22float2(*(__half2*)&v.w);
            float* d = &sx[r][kc * 8];
            d[0] = f0.x; d[1] = f0.y; d[2] = f1.x; d[3] = f1.y;
            d[4] = f2.x; d[5] = f2.y; d[6] = f3.x; d[7] = f3.y;
        }
    } else {
        const float* in = (const float*)inv;
        for (int idx = threadIdx.x; idx < 64 * K / 4; idx += 256) {
            int r = idx / (K / 4), kc = idx % (K / 4);
            float4 v = {0, 0, 0, 0};
            if (r < nvalid) v = *(const float4*)&in[(size_t)(row0 + r) * K + kc * 4];
            *(float4*)&sx[r][kc * 4] = v;
        }
    }
    for (int idx = threadIdx.x; idx < K * C / 4; idx += 256)
        *(float4*)&sW[idx * 4] = *(const float4*)&W[idx * 4];
    __syncthreads();

    int g  = threadIdx.x >> 4;
    int ci = threadIdx.x & 15;
    int r0 = g * 4;
    int c0 = ci * CPT;

    if constexpr (CPT == 4) {
        float4 acc0 = {0,0,0,0}, acc1 = {0,0,0,0}, acc2 = {0,0,0,0}, acc3 = {0,0,0,0};
        for (int k = 0; k < K; k += 4) {
            float4 w0 = *(const float4*)&sW[(k + 0) * C + c0];
            float4 w1 = *(const float4*)&sW[(k + 1) * C + c0];
            float4 w2 = *(const float4*)&sW[(k + 2) * C + c0];
            float4 w3 = *(const float4*)&sW[(k + 3) * C + c0];
            float4 x0 = *(const float4*)&sx[r0 + 0][k];
            float4 x1 = *(const float4*)&sx[r0 + 1][k];
            float4 x2 = *(const float4*)&sx[r0 + 2][k];
            float4 x3 = *(const float4*)&sx[r0 + 3][k];
#define STEP(A, X) \
            A.x = fmaf(X.x, w0.x, A.x); A.y = fmaf(X.x, w0.y, A.y); \
            A.z = fmaf(X.x, w0.z, A.z); A.w = fmaf(X.x, w0.w, A.w); \
            A.x = fmaf(X.y, w1.x, A.x); A.y = fmaf(X.y, w1.y, A.y); \
            A.z = fmaf(X.y, w1.z, A.z); A.w = fmaf(X.y, w1.w, A.w); \
            A.x = fmaf(X.z, w2.x, A.x); A.y = fmaf(X.z, w2.y, A.y); \
            A.z = fmaf(X.z, w2.z, A.z); A.w = fmaf(X.z, w2.w, A.w); \
            A.x = fmaf(X.w, w3.x, A.x); A.y = fmaf(X.w, w3.y, A.y); \
            A.z = fmaf(X.w, w3.z, A.z); A.w = fmaf(X.w, w3.w, A.w);
            STEP(acc0, x0) STEP(acc1, x1) STEP(acc2, x2) STEP(acc3, x3)
#undef STEP
        }
        if constexpr (OUT_HALF) {
            __half* hh = (__half*)hv;
            auto sth = [&](int r, float4 a) {
                if (r0 + r < nvalid) {
                    size_t base = (size_t)(row0 + r0 + r) * C + c0;
                    *(__half2*)&hh[base]     = __floats2half2_rn(a.x, a.y);
                    *(__half2*)&hh[base + 2] = __floats2half2_rn(a.z, a.w);
                }
            };
            sth(0, acc0); sth(1, acc1); sth(2, acc2); sth(3, acc3);
        } else {
            float* h = (float*)hv;
            if (r0 + 0 < nvalid) *(float4*)&h[(size_t)(row0 + r0 + 0) * C + c0] = acc0;
            if (r0 + 1 < nvalid) *(float4*)&h[(size_t)(row0 + r0 + 1) * C + c0] = acc1;
            if (r0 + 2 < nvalid) *(float4*)&h[(size_t)(row0 + r0 + 2) * C + c0] = acc2;
            if (r0 + 3 < nvalid) *(float4*)&h[(size_t)(row0 + r0 + 3) * C + c0] = acc3;
        }
        float4 asv = *(const float4*)&a_src[c0];
        float4 adv = *(const float4*)&a_dst[c0];
        float vs0 = acc0.x*asv.x + acc0.y*asv.y + acc0.z*asv.z + acc0.w*asv.w;
        float vs1 = acc1.x*asv.x + acc1.y*asv.y + acc1.z*asv.z + acc1.w*asv.w;
        float vs2 = acc2.x*asv.x + acc2.y*asv.y + acc2.z*asv.z + acc2.w*asv.w;
        float vs3 = acc3.x*asv.x + acc3.y*asv.y + acc3.z*asv.z + acc3.w*asv.w;
        float vd0 = acc0.x*adv.x + acc0.y*adv.y + acc0.z*adv.z + acc0.w*adv.w;
        float vd1 = acc1.x*adv.x + acc1.y*adv.y + acc1.z*adv.z + acc1.w*adv.w;
        float vd2 = acc2.x*adv.x + acc2.y*adv.y + acc2.z*adv.z + acc2.w*adv.w;
        float vd3 = acc3.x*adv.x + acc3.y*adv.y + acc3.z*adv.z + acc3.w*adv.w;
#pragma unroll
        for (int off = 1; off < 16; off <<= 1) {
            vs0 += __shfl_xor(vs0, off); vs1 += __shfl_xor(vs1, off);
            vs2 += __shfl_xor(vs2, off); vs3 += __shfl_xor(vs3, off);
            vd0 += __shfl_xor(vd0, off); vd1 += __shfl_xor(vd1, off);
            vd2 += __shfl_xor(vd2, off); vd3 += __shfl_xor(vd3, off);
        }
        if (ci == 0) {
            if (r0 + 0 < nvalid) { as_[row0+r0+0] = vs0; ad_[row0+r0+0] = vd0; }
            if (r0 + 1 < nvalid) { as_[row0+r0+1] = vs1; ad_[row0+r0+1] = vd1; }
            if (r0 + 2 < nvalid) { as_[row0+r0+2] = vs2; ad_[row0+r0+2] = vd2; }
            if (r0 + 3 < nvalid) { as_[row0+r0+3] = vs3; ad_[row0+r0+3] = vd3; }
        }
    } else {                               // CPT == 1  (C = 16)
        float s0 = 0.f, s1 = 0.f, s2 = 0.f, s3 = 0.f;
        for (int k = 0; k < K; k += 4) {
            float w0 = sW[(k + 0) * C + c0];
            float w1 = sW[(k + 1) * C + c0];
            float w2 = sW[(k + 2) * C + c0];
            float w3 = sW[(k + 3) * C + c0];
            float4 x0 = *(const float4*)&sx[r0 + 0][k];
            float4 x1 = *(const float4*)&sx[r0 + 1][k];
            float4 x2 = *(const float4*)&sx[r0 + 2][k];
            float4 x3 = *(const float4*)&sx[r0 + 3][k];
            s0 = fmaf(x0.x,w0, fmaf(x0.y,w1, fmaf(x0.z,w2, fmaf(x0.w,w3, s0))));
            s1 = fmaf(x1.x,w0, fmaf(x1.y,w1, fmaf(x1.z,w2, fmaf(x1.w,w3, s1))));
            s2 = fmaf(x2.x,w0, fmaf(x2.y,w1, fmaf(x2.z,w2, fmaf(x2.w,w3, s2))));
            s3 = fmaf(x3.x,w0, fmaf(x3.y,w1, fmaf(x3.z,w2, fmaf(x3.w,w3, s3))));
        }
        if constexpr (OUT_HALF) {
            __half* hh = (__half*)hv;
            if (r0 + 0 < nvalid) hh[(size_t)(row0+r0+0) * C + c0] = __float2half_rn(s0);
            if (r0 + 1 < nvalid) hh[(size_t)(row0+r0+1) * C + c0] = __float2half_rn(s1);
            if (r0 + 2 < nvalid) hh[(size_t)(row0+r0+2) * C + c0] = __float2half_rn(s2);
            if (r0 + 3 < nvalid) hh[(size_t)(row0+r0+3) * C + c0] = __float2half_rn(s3);
        } else {
            float* h = (float*)hv;
            if (r0 + 0 < nvalid) h[(size_t)(row0+r0+0) * C + c0] = s0;
            if (r0 + 1 < nvalid) h[(size_t)(row0+r0+1) * C + c0] = s1;
            if (r0 + 2 < nvalid) h[(size_t)(row0+r0+2) * C + c0] = s2;
            if (r0 + 3 < nvalid) h[(size_t)(row0+r0+3) * C + c0] = s3;
        }
        float as0 = a_src[c0], ad0 = a_dst[c0];
        float vs0 = s0*as0, vs1 = s1*as0, vs2 = s2*as0, vs3 = s3*as0;
        float vd0 = s0*ad0, vd1 = s1*ad0, vd2 = s2*ad0, vd3 = s3*ad0;
#pragma unroll
        for (int off = 1; off < 16; off <<= 1) {
            vs0 += __shfl_xor(vs0, off); vs1 += __shfl_xor(vs1, off);
            vs2 += __shfl_xor(vs2, off); vs3 += __shfl_xor(vs3, off);
            vd0 += __shfl_xor(vd0, off); vd1 += __shfl_xor(vd1, off);
            vd2 += __shfl_xor(vd2, off); vd3 += __shfl_xor(vd3, off);
        }
        if (ci == 0) {
            if (r0 + 0 < nvalid) { as_[row0+r0+0] = vs0; ad_[row0+r0+0] = vd0; }
            if (r0 + 1 < nvalid) { as_[row0+r0+1] = vs1; ad_[row0+r0+1] = vd1; }
            if (r0 + 2 < nvalid) { as_[row0+r0+2] = vs2; ad_[row0+r0+2] = vd2; }
            if (r0 + 3 < nvalid) { as_[row0+r0+3] = vs3; ad_[row0+r0+3] = vd3; }
        }
    }
}

// ================= fused single-pass softmax + aggregation =================
// fp16 h tables. Cooperative alpha (1 exp/edge, coalesced); shfl-distributed;
// fp32 accumulation. All shfls exec-uniform (stripe-rounded bounds).

__device__ __forceinline__ float leaky(float e) {
    return (e >= 0.f) ? e : 0.2f * e;
}

__device__ __forceinline__ void hacc8(uint4 r, float w, float4& accL, float4& accH) {
    float2 f0 = __half22float2(*(__half2*)&r.x);
    float2 f1 = __half22float2(*(__half2*)&r.y);
    float2 f2 = __half22float2(*(__half2*)&r.z);
    float2 f3 = __half22float2(*(__half2*)&r.w);
    accL.x = fmaf(w, f0.x, accL.x); accL.y = fmaf(w, f0.y, accL.y);
    accL.z = fmaf(w, f1.x, accL.z); accL.w = fmaf(w, f1.y, accL.w);
    accH.x = fmaf(w, f2.x, accH.x); accH.y = fmaf(w, f2.y, accH.y);
    accH.z = fmaf(w, f3.x, accH.z); accH.w = fmaf(w, f3.y, accH.w);
}

// 64-ch fp16 table (128 B rows): 8 lanes/edge, 8 edge groups; fp16 out (aHalf)
template<bool RELU>
__global__ __launch_bounds__(256) void agg64h(
        const __half* __restrict__ h, const float* __restrict__ as_, const float* __restrict__ ad_,
        const int* __restrict__ rowptr, const int* __restrict__ csr_src,
        const float* __restrict__ bias, __half* __restrict__ out, int n)
{
    int node = (blockIdx.x * blockDim.x + threadIdx.x) >> 6;
    if (node >= n) return;
    int lane = threadIdx.x & 63;
    int g  = lane >> 3;       // edge group 0..7 (slots j = g+8k)
    int c8 = lane & 7;        // 8-channel slice (16 B of the 128 B row)
    int start = rowptr[node], end = rowptr[node + 1];
    float adn = ad_[node];
    const char* hb = (const char*)h + (size_t)c8 * 16;

    float4 accL = {0,0,0,0}, accH = {0,0,0,0};
    float dsum = 0.f;

    for (int chunk = start; chunk < end; chunk += 64) {
        int e_i = chunk + lane;
        int soff = 0; float aw = 0.f;
        if (e_i < end) {
            int ssrc = csr_src[e_i];                   // coalesced
            soff = ssrc << 7;                          // 128 B rows
            aw = __expf(leaky(as_[ssrc] + adn));       // 1 exp per edge
        }
        dsum += aw;
        int nv = end - chunk; if (nv > 64) nv = 64;
        int nvu = (nv + 31) & ~31;                     // stripes of 32 slots
        for (int j = g; j < nvu; j += 32) {            // 4 gathers in flight
            int   o0 = __shfl(soff, j),      o1 = __shfl(soff, j + 8);
            int   o2 = __shfl(soff, j + 16), o3 = __shfl(soff, j + 24);
            float w0 = __shfl(aw, j),        w1 = __shfl(aw, j + 8);
            float w2 = __shfl(aw, j + 16),   w3 = __shfl(aw, j + 24);
            uint4 r0 = *(const uint4*)(hb + o0);
            uint4 r1 = *(const uint4*)(hb + o1);
            uint4 r2 = *(const uint4*)(hb + o2);
            uint4 r3 = *(const uint4*)(hb + o3);
            hacc8(r0, w0, accL, accH); hacc8(r1, w1, accL, accH);
            hacc8(r2, w2, accL, accH); hacc8(r3, w3, accL, accH);
        }
    }
#pragma unroll
    for (int off = 8; off <= 32; off <<= 1) {          // combine 8 edge groups
        accL.x += __shfl_xor(accL.x, off); accL.y += __shfl_xor(accL.y, off);
        accL.z += __shfl_xor(accL.z, off); accL.w += __shfl_xor(accL.w, off);
        accH.x += __shfl_xor(accH.x, off); accH.y += __shfl_xor(accH.y, off);
        accH.z += __shfl_xor(accH.z, off); accH.w += __shfl_xor(accH.w, off);
    }
#pragma unroll
    for (int off = 1; off <= 32; off <<= 1) dsum += __shfl_xor(dsum, off);

    if (g == 0) {
        float inv = 1.f / (dsum + 1e-16f);
        float4 bl = *(const float4*)&bias[c8 * 8];
        float4 bh = *(const float4*)&bias[c8 * 8 + 4];
        float4 ol, oh;
        ol.x = fmaf(accL.x, inv, bl.x); ol.y = fmaf(accL.y, inv, bl.y);
        ol.z = fmaf(accL.z, inv, bl.z); ol.w = fmaf(accL.w, inv, bl.w);
        oh.x = fmaf(accH.x, inv, bh.x); oh.y = fmaf(accH.y, inv, bh.y);
        oh.z = fmaf(accH.z, inv, bh.z); oh.w = fmaf(accH.w, inv, bh.w);
        if (RELU) {
            ol.x = fmaxf(ol.x, 0.f); ol.y = fmaxf(ol.y, 0.f);
            ol.z = fmaxf(ol.z, 0.f); ol.w = fmaxf(ol.w, 0.f);
            oh.x = fmaxf(oh.x, 0.f); oh.y = fmaxf(oh.y, 0.f);
            oh.z = fmaxf(oh.z, 0.f); oh.w = fmaxf(oh.w, 0.f);
        }
        __half2 p0 = __floats2half2_rn(ol.x, ol.y);
        __half2 p1 = __floats2half2_rn(ol.z, ol.w);
        __half2 p2 = __floats2half2_rn(oh.x, oh.y);
        __half2 p3 = __floats2half2_rn(oh.z, oh.w);
        uint4 pk;
        pk.x = *(unsigned*)&p0; pk.y = *(unsigned*)&p1;
        pk.z = *(unsigned*)&p2; pk.w = *(unsigned*)&p3;
        *(uint4*)&out[(size_t)node * 64 + c8 * 8] = pk;
    }
}

// 16-ch fp16 table (32 B rows): 2 lanes/edge, 32 edge groups; fp32 out (d_out)
template<bool RELU>
__global__ __launch_bounds__(256) void agg16h(
        const __half* __restrict__ h, const float* __restrict__ as_, const float* __restrict__ ad_,
        const int* __restrict__ rowptr, const int* __restrict__ csr_src,
        const float* __restrict__ bias, float* __restrict__ out, int n)
{
    int node = (blockIdx.x * blockDim.x + threadIdx.x) >> 6;
    if (node >= n) return;
    int lane = threadIdx.x & 63;
    int g   = lane >> 1;      // edge group 0..31 (slots j = g+32k)
    int c16 = lane & 1;       // 16 B half-slice of the 32 B row
    int start = rowptr[node], end = rowptr[node + 1];
    float adn = ad_[node];
    const char* hb = (const char*)h + (size_t)c16 * 16;

    float4 accL = {0,0,0,0}, accH = {0,0,0,0};
    float dsum = 0.f;

    for (int chunk = start; chunk < end; chunk += 64) {
        int e_i = chunk + lane;
        int soff = 0; float aw = 0.f;
        if (e_i < end) {
            int ssrc = csr_src[e_i];
            soff = ssrc << 5;                          // 32 B rows
            aw = __expf(leaky(as_[ssrc] + adn));
        }
        dsum += aw;
        int nv = end - chunk; if (nv > 64) nv = 64;
        int nvu = (nv + 31) & ~31;                     // stripes of 32 slots
        for (int j = g; j < nvu; j += 32) {            // all lanes active at shfl
            int   o0 = __shfl(soff, j);
            float w0 = __shfl(aw, j);
            uint4 r0 = *(const uint4*)(hb + o0);
            hacc8(r0, w0, accL, accH);
        }
    }
#pragma unroll
    for (int off = 2; off <= 32; off <<= 1) {          // combine 32 edge groups
        accL.x += __shfl_xor(accL.x, off); accL.y += __shfl_xor(accL.y, off);
        accL.z += __shfl_xor(accL.z, off); accL.w += __shfl_xor(accL.w, off);
        accH.x += __shfl_xor(accH.x, off); accH.y += __shfl_xor(accH.y, off);
        accH.z += __shfl_xor(accH.z, off); accH.w += __shfl_xor(accH.w, off);
    }
#pragma unroll
    for (int off = 1; off <= 32; off <<= 1) dsum += __shfl_xor(dsum, off);

    if (g == 0) {                                      // lanes 0,1
        float inv = 1.f / (dsum + 1e-16f);
        float4 bl = *(const float4*)&bias[c16 * 8];
        float4 bh = *(const float4*)&bias[c16 * 8 + 4];
        float4 ol, oh;
        ol.x = fmaf(accL.x, inv, bl.x); ol.y = fmaf(accL.y, inv, bl.y);
        ol.z = fmaf(accL.z, inv, bl.z); ol.w = fmaf(accL.w, inv, bl.w);
        oh.x = fmaf(accH.x, inv, bh.x); oh.y = fmaf(accH.y, inv, bh.y);
        oh.z = fmaf(accH.z, inv, bh.z); oh.w = fmaf(accH.w, inv, bh.w);
        if (RELU) {
            ol.x = fmaxf(ol.x, 0.f); ol.y = fmaxf(ol.y, 0.f);
            ol.z = fmaxf(ol.z, 0.f); ol.w = fmaxf(ol.w, 0.f);
            oh.x = fmaxf(oh.x, 0.f); oh.y = fmaxf(oh.y, 0.f);
            oh.z = fmaxf(oh.z, 0.f); oh.w = fmaxf(oh.w, 0.f);
        }
        *(float4*)&out[(size_t)node * 16 + c16 * 8]     = ol;
        *(float4*)&out[(size_t)node * 16 + c16 * 8 + 4] = oh;
    }
}

// ================= launch =================

extern "C" void kernel_launch(void* const* d_in, const int* in_sizes, int n_in,
                              void* d_out, int out_size, void* d_ws, size_t ws_size,
                              hipStream_t stream) {
    const float* x   = (const float*)d_in[0];
    const int*   ei  = (const int*)  d_in[1];
    const float* W1  = (const float*)d_in[3];
    const float* as1 = (const float*)d_in[4];
    const float* ad1 = (const float*)d_in[5];
    const float* b1  = (const float*)d_in[6];
    const float* W2  = (const float*)d_in[7];
    const float* as2 = (const float*)d_in[8];
    const float* ad2 = (const float*)d_in[9];
    const float* b2  = (const float*)d_in[10];
    const float* W3  = (const float*)d_in[11];
    const float* as3 = (const float*)d_in[12];
    const float* ad3 = (const float*)d_in[13];
    const float* b3  = (const float*)d_in[14];

    const int* srcp = ei;
    const int* dstp = ei + N_EDGES;

    char* ws = (char*)d_ws;
    size_t off = 0;
    auto alloc = [&](size_t bytes) -> void* {
        void* p = ws + off;
        off = (off + bytes + 255) & ~(size_t)255;
        return p;
    };
    int*   bhist_t = (int*)   alloc((size_t)NBUCK * NBLK * sizeof(int));
    int*   btot    = (int*)   alloc(NBUCK * sizeof(int));
    int*   rowptr  = (int*)   alloc((N_NODES + 1) * sizeof(int));
    int*   csr_src = (int*)   alloc(N_EDGES * sizeof(int));
    float* asb     = (float*) alloc(N_NODES * sizeof(float));
    float* adb     = (float*) alloc(N_NODES * sizeof(float));
    __half* hHalf  = (__half*)alloc((size_t)N_NODES * 64 * sizeof(__half));
    __half* aHalf  = (__half*)alloc((size_t)N_NODES * 64 * sizeof(__half));
    __half* h16    = (__half*)alloc((size_t)N_NODES * 16 * sizeof(__half));
    unsigned* packed = (unsigned*)alloc((size_t)N_EDGES * sizeof(unsigned));

    bucket_hist    <<<NBLK,  256, 0, stream>>>(dstp, bhist_t, N_EDGES);
    bucket_totals  <<<NBUCK, 256, 0, stream>>>(bhist_t, btot);
    rewrite_offsets<<<NBUCK, 64,  0, stream>>>(bhist_t, btot, rowptr);
    bucket_scatter <<<NBLK,  256, 0, stream>>>(srcp, dstp, bhist_t, packed, N_EDGES);
    csr_finalize   <<<NBUCK, 512, 0, stream>>>(packed, btot, rowptr, csr_src);

    const int NB64 = (N_NODES + 63) / 64;
    const int NB4  = (N_NODES + 3) / 4;

    // layer 1: 128 -> 64, relu  (h fp16, a1 fp16)
    gemm_alpha<128, 64, false, true><<<NB64, 256, 0, stream>>>(x, W1, as1, ad1, hHalf, asb, adb, N_NODES);
    agg64h<true><<<NB4, 256, 0, stream>>>(hHalf, asb, adb, rowptr, csr_src, b1, aHalf, N_NODES);

    // layer 2: 64 -> 64, relu  (h fp16, a2 fp16)
    gemm_alpha<64, 64, true, true><<<NB64, 256, 0, stream>>>(aHalf, W2, as2, ad2, hHalf, asb, adb, N_NODES);
    agg64h<true><<<NB4, 256, 0, stream>>>(hHalf, asb, adb, rowptr, csr_src, b2, aHalf, N_NODES);

    // layer 3: 64 -> 16, no relu  (h fp16 table, fp32 out)
    gemm_alpha<64, 16, true, true><<<NB64, 256, 0, stream>>>(aHalf, W3, as3, ad3, h16, asb, adb, N_NODES);
    agg16h<false><<<NB4, 256, 0, stream>>>(h16, asb, adb, rowptr, csr_src, b3, (float*)d_out, N_NODES);
}

// Round 12
// 184.393 us; speedup vs baseline: 1.0279x; 1.0279x over previous
//
#include <hip/hip_runtime.h>
#include <hip/hip_fp16.h>
#include <math.h>

#define N_NODES 50000
#define N_EDGES 1600000
#define BSH 8                                   // 256 nodes per bucket
#define NBUCK ((N_NODES + 255) >> BSH)          // 196
#define EPB 2048                                // edges per scatter/hist block
#define NBLK ((N_EDGES + EPB - 1) / EPB)        // 782

// ================= CSR build (atomic-free at global scope) =================

__global__ __launch_bounds__(256) void bucket_hist(const int* __restrict__ dst,
                                                   int* __restrict__ bhist_t, int e) {
    __shared__ int h[NBUCK];
    for (int i = threadIdx.x; i < NBUCK; i += 256) h[i] = 0;
    __syncthreads();
    int base = blockIdx.x * EPB;
#pragma unroll
    for (int j = 0; j < EPB / 256; ++j) {
        int i = base + j * 256 + threadIdx.x;
        if (i < e) atomicAdd(&h[dst[i] >> BSH], 1);
    }
    __syncthreads();
    for (int i = threadIdx.x; i < NBUCK; i += 256)
        bhist_t[i * NBLK + blockIdx.x] = h[i];
}

__global__ __launch_bounds__(256) void bucket_totals(const int* __restrict__ bhist_t,
                                                     int* __restrict__ btot) {
    int b = blockIdx.x;
    const int* col = bhist_t + (size_t)b * NBLK;
    int s = 0;
    for (int i = threadIdx.x; i < NBLK; i += 256) s += col[i];
#pragma unroll
    for (int off = 1; off < 64; off <<= 1) s += __shfl_xor(s, off);
    __shared__ int red[4];
    if ((threadIdx.x & 63) == 0) red[threadIdx.x >> 6] = s;
    __syncthreads();
    if (threadIdx.x == 0)
        btot[b] = red[0] + red[1] + red[2] + red[3];
}

// one wave per bucket: internal prefix over btot, then column scan + rewrite
__global__ __launch_bounds__(64) void rewrite_offsets(int* __restrict__ bhist_t,
                                                      const int* __restrict__ btot,
                                                      int* __restrict__ rowptr) {
    int b = blockIdx.x;
    int lane = threadIdx.x;
    int pre = 0;                                  // bbase[b] computed in-wave
    for (int i = lane; i < NBUCK; i += 64) if (i < b) pre += btot[i];
#pragma unroll
    for (int off = 1; off < 64; off <<= 1) pre += __shfl_xor(pre, off);
    if (b == 0 && lane == 0) rowptr[N_NODES] = N_EDGES;

    int* col = bhist_t + (size_t)b * NBLK;
    __shared__ int buf[NBLK];
    for (int i = lane; i < NBLK; i += 64) buf[i] = col[i];
    __syncthreads();
    constexpr int CH = (NBLK + 63) / 64;
    int lo = lane * CH;
    int hi = lo + CH; if (hi > NBLK) hi = NBLK;
    int s = 0;
    for (int i = lo; i < hi; ++i) s += buf[i];
    int inc = s;
#pragma unroll
    for (int off = 1; off < 64; off <<= 1) {
        int t = __shfl_up(inc, off);
        if (lane >= off) inc += t;
    }
    int run = pre + inc - s;
    for (int i = lo; i < hi; ++i) { int c = buf[i]; col[i] = run; run += c; }
}

// LDS counting-sort scatter: stage edges bucket-sorted in LDS, then stream out
// so global writes are sequential within each bucket run (few streams/wave).
__global__ __launch_bounds__(256) void bucket_scatter(const int* __restrict__ src,
                                                      const int* __restrict__ dst,
                                                      const int* __restrict__ bhist_t,
                                                      unsigned* __restrict__ packed, int e) {
    __shared__ int lcnt[NBUCK];
    __shared__ int lbase[NBUCK];
    __shared__ int gbase[NBUCK];
    __shared__ unsigned stage[EPB];
    __shared__ unsigned char sbk[EPB];
    __shared__ int wsum[4];
    int r = blockIdx.x;
    for (int i = threadIdx.x; i < NBUCK; i += 256) {
        lcnt[i] = 0;
        gbase[i] = bhist_t[i * NBLK + r];
    }
    __syncthreads();
    int base = r * EPB;
    int bk[EPB / 256], lrank[EPB / 256];
    unsigned pk[EPB / 256];
    bool val[EPB / 256];
#pragma unroll
    for (int j = 0; j < EPB / 256; ++j) {
        int i = base + j * 256 + threadIdx.x;
        val[j] = (i < e);
        if (val[j]) {
            int d = dst[i];
            bk[j] = d >> BSH;
            pk[j] = (unsigned)src[i] | ((unsigned)(d & ((1 << BSH) - 1)) << 16);
            lrank[j] = atomicAdd(&lcnt[bk[j]], 1);
        }
    }
    __syncthreads();
    // exclusive scan of lcnt (196 bins) via 4-wave shfl scan
    {
        int lane = threadIdx.x & 63, w = threadIdx.x >> 6;
        int v = (threadIdx.x < NBUCK) ? lcnt[threadIdx.x] : 0;
        int inc = v;
#pragma unroll
        for (int off = 1; off < 64; off <<= 1) {
            int t = __shfl_up(inc, off);
            if (lane >= off) inc += t;
        }
        if (lane == 63) wsum[w] = inc;
        __syncthreads();
        int woff = 0;
#pragma unroll
        for (int k = 0; k < 3; ++k) if (k < w) woff += wsum[k];
        if (threadIdx.x < NBUCK) lbase[threadIdx.x] = woff + inc - v;
    }
    __syncthreads();
#pragma unroll
    for (int j = 0; j < EPB / 256; ++j) {
        if (val[j]) {
            int slot = lbase[bk[j]] + lrank[j];
            stage[slot] = pk[j];
            sbk[slot] = (unsigned char)bk[j];
        }
    }
    __syncthreads();
    int vn = e - base; if (vn > EPB) vn = EPB;
    for (int i = threadIdx.x; i < vn; i += 256) {
        int b = sbk[i];
        packed[gbase[b] + (i - lbase[b])] = stage[i];   // sequential within runs
    }
}

__global__ __launch_bounds__(512) void csr_finalize(const unsigned* __restrict__ packed,
                                                    const int* __restrict__ btot,
                                                    int* __restrict__ rowptr,
                                                    unsigned short* __restrict__ csr_src) {
    int b = blockIdx.x;
    __shared__ int sb[2];
    if (threadIdx.x < 64) {                       // wave 0: prefix over btot
        int pre = 0, tot = 0;
        for (int i = threadIdx.x; i < NBUCK; i += 64) {
            int v = btot[i];
            if (i < b) pre += v;
            if (i == b) tot = v;
        }
#pragma unroll
        for (int off = 1; off < 64; off <<= 1) {
            pre += __shfl_xor(pre, off);
            tot += __shfl_xor(tot, off);
        }
        if (threadIdx.x == 0) { sb[0] = pre; sb[1] = pre + tot; }
    }
    __syncthreads();
    int s0 = sb[0], s1 = sb[1];
    int cnt = s1 - s0;
    __shared__ int ncnt[256];
    __shared__ int ncur[256];
    __shared__ int wsum[4];
    if (threadIdx.x < 256) ncnt[threadIdx.x] = 0;
    __syncthreads();
    for (int i = threadIdx.x; i < cnt; i += 512)
        atomicAdd(&ncnt[packed[s0 + i] >> 16], 1);
    __syncthreads();
    int lane = threadIdx.x & 63, w = threadIdx.x >> 6;
    int v = 0, inc = 0;
    if (threadIdx.x < 256) {
        v = ncnt[threadIdx.x]; inc = v;
#pragma unroll
        for (int off = 1; off < 64; off <<= 1) {
            int t = __shfl_up(inc, off);
            if (lane >= off) inc += t;
        }
        if (lane == 63) wsum[w] = inc;
    }
    __syncthreads();
    if (threadIdx.x < 256) {
        int woff = 0;
#pragma unroll
        for (int k = 0; k < 3; ++k) if (k < w) woff += wsum[k];
        int excl = woff + inc - v;
        int node = (b << BSH) + threadIdx.x;
        if (node < N_NODES) rowptr[node] = s0 + excl;
        ncur[threadIdx.x] = s0 + excl;
    }
    __syncthreads();
    for (int i = threadIdx.x; i < cnt; i += 512) {
        unsigned p = packed[s0 + i];
        int pos = atomicAdd(&ncur[p >> 16], 1);
        csr_src[pos] = (unsigned short)(p & 0xFFFFu);
    }
}

// ================= register-tiled GEMM + fused alpha =================
// IN_HALF: input activations fp16; OUT_HALF: h table stored fp16.
// All accumulation + as_/ad_ stay fp32.

template<int K, int C, bool IN_HALF, bool OUT_HALF>
__global__ __launch_bounds__(256) void gemm_alpha(
        const void* __restrict__ inv, const float* __restrict__ W,
        const float* __restrict__ a_src, const float* __restrict__ a_dst,
        void* __restrict__ hv, float* __restrict__ as_, float* __restrict__ ad_, int n)
{
    constexpr int CPT = C / 16;
    constexpr int KP = K + 4;
    __shared__ float sx[64][KP];
    __shared__ float sW[K * C];
    int row0 = blockIdx.x * 64;
    int nvalid = n - row0;

    if constexpr (IN_HALF) {
        const __half* inh = (const __half*)inv;
        for (int idx = threadIdx.x; idx < 64 * K / 8; idx += 256) {
            int r = idx / (K / 8), kc = idx % (K / 8);
            uint4 v = {0u, 0u, 0u, 0u};
            if (r < nvalid) v = *(const uint4*)&inh[(size_t)(row0 + r) * K + kc * 8];
            float2 f0 = __half22float2(*(__half2*)&v.x);
            float2 f1 = __half22float2(*(__half2*)&v.y);
            float2 f2 = __half22float2(*(__half2*)&v.z);
            float2 f3 = __half22float2(*(__half2*)&v.w);
            float* d = &sx[r][kc * 8];
            d[0] = f0.x; d[1] = f0.y; d[2] = f1.x; d[3] = f1.y;
            d[4] = f2.x; d[5] = f2.y; d[6] = f3.x; d[7] = f3.y;
        }
    } else {
        const float* in = (const float*)inv;
        for (int idx = threadIdx.x; idx < 64 * K / 4; idx += 256) {
            int r = idx / (K / 4), kc = idx % (K / 4);
            float4 v = {0, 0, 0, 0};
            if (r < nvalid) v = *(const float4*)&in[(size_t)(row0 + r) * K + kc * 4];
            *(float4*)&sx[r][kc * 4] = v;
        }
    }
    for (int idx = threadIdx.x; idx < K * C / 4; idx += 256)
        *(float4*)&sW[idx * 4] = *(const float4*)&W[idx * 4];
    __syncthreads();

    int g  = threadIdx.x >> 4;
    int ci = threadIdx.x & 15;
    int r0 = g * 4;
    int c0 = ci * CPT;

    if constexpr (CPT == 4) {
        float4 acc0 = {0,0,0,0}, acc1 = {0,0,0,0}, acc2 = {0,0,0,0}, acc3 = {0,0,0,0};
        for (int k = 0; k < K; k += 4) {
            float4 w0 = *(const float4*)&sW[(k + 0) * C + c0];
            float4 w1 = *(const float4*)&sW[(k + 1) * C + c0];
            float4 w2 = *(const float4*)&sW[(k + 2) * C + c0];
            float4 w3 = *(const float4*)&sW[(k + 3) * C + c0];
            float4 x0 = *(const float4*)&sx[r0 + 0][k];
            float4 x1 = *(const float4*)&sx[r0 + 1][k];
            float4 x2 = *(const float4*)&sx[r0 + 2][k];
            float4 x3 = *(const float4*)&sx[r0 + 3][k];
#define STEP(A, X) \
            A.x = fmaf(X.x, w0.x, A.x); A.y = fmaf(X.x, w0.y, A.y); \
            A.z = fmaf(X.x, w0.z, A.z); A.w = fmaf(X.x, w0.w, A.w); \
            A.x = fmaf(X.y, w1.x, A.x); A.y = fmaf(X.y, w1.y, A.y); \
            A.z = fmaf(X.y, w1.z, A.z); A.w = fmaf(X.y, w1.w, A.w); \
            A.x = fmaf(X.z, w2.x, A.x); A.y = fmaf(X.z, w2.y, A.y); \
            A.z = fmaf(X.z, w2.z, A.z); A.w = fmaf(X.z, w2.w, A.w); \
            A.x = fmaf(X.w, w3.x, A.x); A.y = fmaf(X.w, w3.y, A.y); \
            A.z = fmaf(X.w, w3.z, A.z); A.w = fmaf(X.w, w3.w, A.w);
            STEP(acc0, x0) STEP(acc1, x1) STEP(acc2, x2) STEP(acc3, x3)
#undef STEP
        }
        if constexpr (OUT_HALF) {
            __half* hh = (__half*)hv;
            auto sth = [&](int r, float4 a) {
                if (r0 + r < nvalid) {
                    size_t base = (size_t)(row0 + r0 + r) * C + c0;
                    *(__half2*)&hh[base]     = __floats2half2_rn(a.x, a.y);
                    *(__half2*)&hh[base + 2] = __floats2half2_rn(a.z, a.w);
                }
            };
            sth(0, acc0); sth(1, acc1); sth(2, acc2); sth(3, acc3);
        } else {
            float* h = (float*)hv;
            if (r0 + 0 < nvalid) *(float4*)&h[(size_t)(row0 + r0 + 0) * C + c0] = acc0;
            if (r0 + 1 < nvalid) *(float4*)&h[(size_t)(row0 + r0 + 1) * C + c0] = acc1;
            if (r0 + 2 < nvalid) *(float4*)&h[(size_t)(row0 + r0 + 2) * C + c0] = acc2;
            if (r0 + 3 < nvalid) *(float4*)&h[(size_t)(row0 + r0 + 3) * C + c0] = acc3;
        }
        float4 asv = *(const float4*)&a_src[c0];
        float4 adv = *(const float4*)&a_dst[c0];
        float vs0 = acc0.x*asv.x + acc0.y*asv.y + acc0.z*asv.z + acc0.w*asv.w;
        float vs1 = acc1.x*asv.x + acc1.y*asv.y + acc1.z*asv.z + acc1.w*asv.w;
        float vs2 = acc2.x*asv.x + acc2.y*asv.y + acc2.z*asv.z + acc2.w*asv.w;
        float vs3 = acc3.x*asv.x + acc3.y*asv.y + acc3.z*asv.z + acc3.w*asv.w;
        float vd0 = acc0.x*adv.x + acc0.y*adv.y + acc0.z*adv.z + acc0.w*adv.w;
        float vd1 = acc1.x*adv.x + acc1.y*adv.y + acc1.z*adv.z + acc1.w*adv.w;
        float vd2 = acc2.x*adv.x + acc2.y*adv.y + acc2.z*adv.z + acc2.w*adv.w;
        float vd3 = acc3.x*adv.x + acc3.y*adv.y + acc3.z*adv.z + acc3.w*adv.w;
#pragma unroll
        for (int off = 1; off < 16; off <<= 1) {
            vs0 += __shfl_xor(vs0, off); vs1 += __shfl_xor(vs1, off);
            vs2 += __shfl_xor(vs2, off); vs3 += __shfl_xor(vs3, off);
            vd0 += __shfl_xor(vd0, off); vd1 += __shfl_xor(vd1, off);
            vd2 += __shfl_xor(vd2, off); vd3 += __shfl_xor(vd3, off);
        }
        if (ci == 0) {
            if (r0 + 0 < nvalid) { as_[row0+r0+0] = vs0; ad_[row0+r0+0] = vd0; }
            if (r0 + 1 < nvalid) { as_[row0+r0+1] = vs1; ad_[row0+r0+1] = vd1; }
            if (r0 + 2 < nvalid) { as_[row0+r0+2] = vs2; ad_[row0+r0+2] = vd2; }
            if (r0 + 3 < nvalid) { as_[row0+r0+3] = vs3; ad_[row0+r0+3] = vd3; }
        }
    } else {                               // CPT == 1  (C = 16)
        float s0 = 0.f, s1 = 0.f, s2 = 0.f, s3 = 0.f;
        for (int k = 0; k < K; k += 4) {
            float w0 = sW[(k + 0) * C + c0];
            float w1 = sW[(k + 1) * C + c0];
            float w2 = sW[(k + 2) * C + c0];
            float w3 = sW[(k + 3) * C + c0];
            float4 x0 = *(const float4*)&sx[r0 + 0][k];
            float4 x1 = *(const float4*)&sx[r0 + 1][k];
            float4 x2 = *(const float4*)&sx[r0 + 2][k];
            float4 x3 = *(const float4*)&sx[r0 + 3][k];
            s0 = fmaf(x0.x,w0, fmaf(x0.y,w1, fmaf(x0.z,w2, fmaf(x0.w,w3, s0))));
            s1 = fmaf(x1.x,w0, fmaf(x1.y,w1, fmaf(x1.z,w2, fmaf(x1.w,w3, s1))));
            s2 = fmaf(x2.x,w0, fmaf(x2.y,w1, fmaf(x2.z,w2, fmaf(x2.w,w3, s2))));
            s3 = fmaf(x3.x,w0, fmaf(x3.y,w1, fmaf(x3.z,w2, fmaf(x3.w,w3, s3))));
        }
        if constexpr (OUT_HALF) {
            __half* hh = (__half*)hv;
            if (r0 + 0 < nvalid) hh[(size_t)(row0+r0+0) * C + c0] = __float2half_rn(s0);
            if (r0 + 1 < nvalid) hh[(size_t)(row0+r0+1) * C + c0] = __float2half_rn(s1);
            if (r0 + 2 < nvalid) hh[(size_t)(row0+r0+2) * C + c0] = __float2half_rn(s2);
            if (r0 + 3 < nvalid) hh[(size_t)(row0+r0+3) * C + c0] = __float2half_rn(s3);
        } else {
            float* h = (float*)hv;
            if (r0 + 0 < nvalid) h[(size_t)(row0+r0+0) * C + c0] = s0;
            if (r0 + 1 < nvalid) h[(size_t)(row0+r0+1) * C + c0] = s1;
            if (r0 + 2 < nvalid) h[(size_t)(row0+r0+2) * C + c0] = s2;
            if (r0 + 3 < nvalid) h[(size_t)(row0+r0+3) * C + c0] = s3;
        }
        float as0 = a_src[c0], ad0 = a_dst[c0];
        float vs0 = s0*as0, vs1 = s1*as0, vs2 = s2*as0, vs3 = s3*as0;
        float vd0 = s0*ad0, vd1 = s1*ad0, vd2 = s2*ad0, vd3 = s3*ad0;
#pragma unroll
        for (int off = 1; off < 16; off <<= 1) {
            vs0 += __shfl_xor(vs0, off); vs1 += __shfl_xor(vs1, off);
            vs2 += __shfl_xor(vs2, off); vs3 += __shfl_xor(vs3, off);
            vd0 += __shfl_xor(vd0, off); vd1 += __shfl_xor(vd1, off);
            vd2 += __shfl_xor(vd2, off); vd3 += __shfl_xor(vd3, off);
        }
        if (ci == 0) {
            if (r0 + 0 < nvalid) { as_[row0+r0+0] = vs0; ad_[row0+r0+0] = vd0; }
            if (r0 + 1 < nvalid) { as_[row0+r0+1] = vs1; ad_[row0+r0+1] = vd1; }
            if (r0 + 2 < nvalid) { as_[row0+r0+2] = vs2; ad_[row0+r0+2] = vd2; }
            if (r0 + 3 < nvalid) { as_[row0+r0+3] = vs3; ad_[row0+r0+3] = vd3; }
        }
    }
}

// ================= fused single-pass softmax + aggregation =================
// fp16 h tables. Cooperative alpha (1 exp/edge, coalesced); shfl-distributed;
// fp32 accumulation. All shfls exec-uniform (stripe-rounded bounds).

__device__ __forceinline__ float leaky(float e) {
    return (e >= 0.f) ? e : 0.2f * e;
}

__device__ __forceinline__ void hacc8(uint4 r, float w, float4& accL, float4& accH) {
    float2 f0 = __half22float2(*(__half2*)&r.x);
    float2 f1 = __half22float2(*(__half2*)&r.y);
    float2 f2 = __half22float2(*(__half2*)&r.z);
    float2 f3 = __half22float2(*(__half2*)&r.w);
    accL.x = fmaf(w, f0.x, accL.x); accL.y = fmaf(w, f0.y, accL.y);
    accL.z = fmaf(w, f1.x, accL.z); accL.w = fmaf(w, f1.y, accL.w);
    accH.x = fmaf(w, f2.x, accH.x); accH.y = fmaf(w, f2.y, accH.y);
    accH.z = fmaf(w, f3.x, accH.z); accH.w = fmaf(w, f3.y, accH.w);
}

// 64-ch fp16 table (128 B rows): 8 lanes/edge, 8 edge groups; fp16 out (aHalf)
template<bool RELU>
__global__ __launch_bounds__(256) void agg64h(
        const __half* __restrict__ h, const float* __restrict__ as_, const float* __restrict__ ad_,
        const int* __restrict__ rowptr, const unsigned short* __restrict__ csr_src,
        const float* __restrict__ bias, __half* __restrict__ out, int n)
{
    int node = (blockIdx.x * blockDim.x + threadIdx.x) >> 6;
    if (node >= n) return;
    int lane = threadIdx.x & 63;
    int g  = lane >> 3;       // edge group 0..7 (slots j = g+8k)
    int c8 = lane & 7;        // 8-channel slice (16 B of the 128 B row)
    int start = rowptr[node], end = rowptr[node + 1];
    float adn = ad_[node];
    const char* hb = (const char*)h + (size_t)c8 * 16;

    float4 accL = {0,0,0,0}, accH = {0,0,0,0};
    float dsum = 0.f;

    for (int chunk = start; chunk < end; chunk += 64) {
        int e_i = chunk + lane;
        int soff = 0; float aw = 0.f;
        if (e_i < end) {
            int ssrc = csr_src[e_i];                   // coalesced (2 B)
            soff = ssrc << 7;                          // 128 B rows
            aw = __expf(leaky(as_[ssrc] + adn));       // 1 exp per edge
        }
        dsum += aw;
        int nv = end - chunk; if (nv > 64) nv = 64;
        int nvu = (nv + 31) & ~31;                     // stripes of 32 slots
        for (int j = g; j < nvu; j += 32) {            // 4 gathers in flight
            int   o0 = __shfl(soff, j),      o1 = __shfl(soff, j + 8);
            int   o2 = __shfl(soff, j + 16), o3 = __shfl(soff, j + 24);
            float w0 = __shfl(aw, j),        w1 = __shfl(aw, j + 8);
            float w2 = __shfl(aw, j + 16),   w3 = __shfl(aw, j + 24);
            uint4 r0 = *(const uint4*)(hb + o0);
            uint4 r1 = *(const uint4*)(hb + o1);
            uint4 r2 = *(const uint4*)(hb + o2);
            uint4 r3 = *(const uint4*)(hb + o3);
            hacc8(r0, w0, accL, accH); hacc8(r1, w1, accL, accH);
            hacc8(r2, w2, accL, accH); hacc8(r3, w3, accL, accH);
        }
    }
#pragma unroll
    for (int off = 8; off <= 32; off <<= 1) {          // combine 8 edge groups
        accL.x += __shfl_xor(accL.x, off); accL.y += __shfl_xor(accL.y, off);
        accL.z += __shfl_xor(accL.z, off); accL.w += __shfl_xor(accL.w, off);
        accH.x += __shfl_xor(accH.x, off); accH.y += __shfl_xor(accH.y, off);
        accH.z += __shfl_xor(accH.z, off); accH.w += __shfl_xor(accH.w, off);
    }
#pragma unroll
    for (int off = 1; off <= 32; off <<= 1) dsum += __shfl_xor(dsum, off);

    if (g == 0) {
        float inv = 1.f / (dsum + 1e-16f);
        float4 bl = *(const float4*)&bias[c8 * 8];
        float4 bh = *(const float4*)&bias[c8 * 8 + 4];
        float4 ol, oh;
        ol.x = fmaf(accL.x, inv, bl.x); ol.y = fmaf(accL.y, inv, bl.y);
        ol.z = fmaf(accL.z, inv, bl.z); ol.w = fmaf(accL.w, inv, bl.w);
        oh.x = fmaf(accH.x, inv, bh.x); oh.y = fmaf(accH.y, inv, bh.y);
        oh.z = fmaf(accH.z, inv, bh.z); oh.w = fmaf(accH.w, inv, bh.w);
        if (RELU) {
            ol.x = fmaxf(ol.x, 0.f); ol.y = fmaxf(ol.y, 0.f);
            ol.z = fmaxf(ol.z, 0.f); ol.w = fmaxf(ol.w, 0.f);
            oh.x = fmaxf(oh.x, 0.f); oh.y = fmaxf(oh.y, 0.f);
            oh.z = fmaxf(oh.z, 0.f); oh.w = fmaxf(oh.w, 0.f);
        }
        __half2 p0 = __floats2half2_rn(ol.x, ol.y);
        __half2 p1 = __floats2half2_rn(ol.z, ol.w);
        __half2 p2 = __floats2half2_rn(oh.x, oh.y);
        __half2 p3 = __floats2half2_rn(oh.z, oh.w);
        uint4 pk;
        pk.x = *(unsigned*)&p0; pk.y = *(unsigned*)&p1;
        pk.z = *(unsigned*)&p2; pk.w = *(unsigned*)&p3;
        *(uint4*)&out[(size_t)node * 64 + c8 * 8] = pk;
    }
}

// 16-ch fp16 table (32 B rows): 2 lanes/edge, 32 edge groups; fp32 out (d_out)
template<bool RELU>
__global__ __launch_bounds__(256) void agg16h(
        const __half* __restrict__ h, const float* __restrict__ as_, const float* __restrict__ ad_,
        const int* __restrict__ rowptr, const unsigned short* __restrict__ csr_src,
        const float* __restrict__ bias, float* __restrict__ out, int n)
{
    int node = (blockIdx.x * blockDim.x + threadIdx.x) >> 6;
    if (node >= n) return;
    int lane = threadIdx.x & 63;
    int g   = lane >> 1;      // edge group 0..31 (slots j = g+32k)
    int c16 = lane & 1;       // 16 B half-slice of the 32 B row
    int start = rowptr[node], end = rowptr[node + 1];
    float adn = ad_[node];
    const char* hb = (const char*)h + (size_t)c16 * 16;

    float4 accL = {0,0,0,0}, accH = {0,0,0,0};
    float dsum = 0.f;

    for (int chunk = start; chunk < end; chunk += 64) {
        int e_i = chunk + lane;
        int soff = 0; float aw = 0.f;
        if (e_i < end) {
            int ssrc = csr_src[e_i];
            soff = ssrc << 5;                          // 32 B rows
            aw = __expf(leaky(as_[ssrc] + adn));
        }
        dsum += aw;
        int nv = end - chunk; if (nv > 64) nv = 64;
        int nvu = (nv + 31) & ~31;                     // stripes of 32 slots
        for (int j = g; j < nvu; j += 32) {            // all lanes active at shfl
            int   o0 = __shfl(soff, j);
            float w0 = __shfl(aw, j);
            uint4 r0 = *(const uint4*)(hb + o0);
            hacc8(r0, w0, accL, accH);
        }
    }
#pragma unroll
    for (int off = 2; off <= 32; off <<= 1) {          // combine 32 edge groups
        accL.x += __shfl_xor(accL.x, off); accL.y += __shfl_xor(accL.y, off);
        accL.z += __shfl_xor(accL.z, off); accL.w += __shfl_xor(accL.w, off);
        accH.x += __shfl_xor(accH.x, off); accH.y += __shfl_xor(accH.y, off);
        accH.z += __shfl_xor(accH.z, off); accH.w += __shfl_xor(accH.w, off);
    }
#pragma unroll
    for (int off = 1; off <= 32; off <<= 1) dsum += __shfl_xor(dsum, off);

    if (g == 0) {                                      // lanes 0,1
        float inv = 1.f / (dsum + 1e-16f);
        float4 bl = *(const float4*)&bias[c16 * 8];
        float4 bh = *(const float4*)&bias[c16 * 8 + 4];
        float4 ol, oh;
        ol.x = fmaf(accL.x, inv, bl.x); ol.y = fmaf(accL.y, inv, bl.y);
        ol.z = fmaf(accL.z, inv, bl.z); ol.w = fmaf(accL.w, inv, bl.w);
        oh.x = fmaf(accH.x, inv, bh.x); oh.y = fmaf(accH.y, inv, bh.y);
        oh.z = fmaf(accH.z, inv, bh.z); oh.w = fmaf(accH.w, inv, bh.w);
        if (RELU) {
            ol.x = fmaxf(ol.x, 0.f); ol.y = fmaxf(ol.y, 0.f);
            ol.z = fmaxf(ol.z, 0.f); ol.w = fmaxf(ol.w, 0.f);
            oh.x = fmaxf(oh.x, 0.f); oh.y = fmaxf(oh.y, 0.f);
            oh.z = fmaxf(oh.z, 0.f); oh.w = fmaxf(oh.w, 0.f);
        }
        *(float4*)&out[(size_t)node * 16 + c16 * 8]     = ol;
        *(float4*)&out[(size_t)node * 16 + c16 * 8 + 4] = oh;
    }
}

// ================= launch =================

extern "C" void kernel_launch(void* const* d_in, const int* in_sizes, int n_in,
                              void* d_out, int out_size, void* d_ws, size_t ws_size,
                              hipStream_t stream) {
    const float* x   = (const float*)d_in[0];
    const int*   ei  = (const int*)  d_in[1];
    const float* W1  = (const float*)d_in[3];
    const float* as1 = (const float*)d_in[4];
    const float* ad1 = (const float*)d_in[5];
    const float* b1  = (const float*)d_in[6];
    const float* W2  = (const float*)d_in[7];
    const float* as2 = (const float*)d_in[8];
    const float* ad2 = (const float*)d_in[9];
    const float* b2  = (const float*)d_in[10];
    const float* W3  = (const float*)d_in[11];
    const float* as3 = (const float*)d_in[12];
    const float* ad3 = (const float*)d_in[13];
    const float* b3  = (const float*)d_in[14];

    const int* srcp = ei;
    const int* dstp = ei + N_EDGES;

    char* ws = (char*)d_ws;
    size_t off = 0;
    auto alloc = [&](size_t bytes) -> void* {
        void* p = ws + off;
        off = (off + bytes + 255) & ~(size_t)255;
        return p;
    };
    int*   bhist_t = (int*)   alloc((size_t)NBUCK * NBLK * sizeof(int));
    int*   btot    = (int*)   alloc(NBUCK * sizeof(int));
    int*   rowptr  = (int*)   alloc((N_NODES + 1) * sizeof(int));
    unsigned short* csr_src = (unsigned short*)alloc((size_t)N_EDGES * sizeof(unsigned short));
    float* asb     = (float*) alloc(N_NODES * sizeof(float));
    float* adb     = (float*) alloc(N_NODES * sizeof(float));
    __half* hHalf  = (__half*)alloc((size_t)N_NODES * 64 * sizeof(__half));
    __half* aHalf  = (__half*)alloc((size_t)N_NODES * 64 * sizeof(__half));
    __half* h16    = (__half*)alloc((size_t)N_NODES * 16 * sizeof(__half));
    unsigned* packed = (unsigned*)alloc((size_t)N_EDGES * sizeof(unsigned));

    bucket_hist    <<<NBLK,  256, 0, stream>>>(dstp, bhist_t, N_EDGES);
    bucket_totals  <<<NBUCK, 256, 0, stream>>>(bhist_t, btot);
    rewrite_offsets<<<NBUCK, 64,  0, stream>>>(bhist_t, btot, rowptr);
    bucket_scatter <<<NBLK,  256, 0, stream>>>(srcp, dstp, bhist_t, packed, N_EDGES);
    csr_finalize   <<<NBUCK, 512, 0, stream>>>(packed, btot, rowptr, csr_src);

    const int NB64 = (N_NODES + 63) / 64;
    const int NB4  = (N_NODES + 3) / 4;

    // layer 1: 128 -> 64, relu  (h fp16, a1 fp16)
    gemm_alpha<128, 64, false, true><<<NB64, 256, 0, stream>>>(x, W1, as1, ad1, hHalf, asb, adb, N_NODES);
    agg64h<true><<<NB4, 256, 0, stream>>>(hHalf, asb, adb, rowptr, csr_src, b1, aHalf, N_NODES);

    // layer 2: 64 -> 64, relu  (h fp16, a2 fp16)
    gemm_alpha<64, 64, true, true><<<NB64, 256, 0, stream>>>(aHalf, W2, as2, ad2, hHalf, asb, adb, N_NODES);
    agg64h<true><<<NB4, 256, 0, stream>>>(hHalf, asb, adb, rowptr, csr_src, b2, aHalf, N_NODES);

    // layer 3: 64 -> 16, no relu  (h fp16 table, fp32 out)
    gemm_alpha<64, 16, true, true><<<NB64, 256, 0, stream>>>(aHalf, W3, as3, ad3, h16, asb, adb, N_NODES);
    agg16h<false><<<NB4, 256, 0, stream>>>(h16, asb, adb, rowptr, csr_src, b3, (float*)d_out, N_NODES);
}